// Round 8
// baseline (283.229 us; speedup 1.0000x reference)
//
#include <hip/hip_runtime.h>
#include <hip/hip_bf16.h>

typedef __bf16 bf16;
typedef __bf16 bf16x4 __attribute__((ext_vector_type(4)));
typedef __bf16 bf16x8 __attribute__((ext_vector_type(8)));
typedef float f32x4 __attribute__((ext_vector_type(4)));

#define B_ 16
#define N_ 1024
#define F_ 512

__device__ __forceinline__ float rdv(const void* p, size_t i, int f32) {
  return f32 ? ((const float*)p)[i] : (float)((const bf16*)p)[i];
}

// async global->LDS, 16B per lane; LDS dest = wave-uniform base + lane*16
__device__ __forceinline__ void gld16(const bf16* g, bf16* l) {
  __builtin_amdgcn_global_load_lds(
      (const __attribute__((address_space(1))) unsigned int*)g,
      (__attribute__((address_space(3))) unsigned int*)l, 16, 0, 0);
}

// Detect input dtype from W1's raw words (bf16 pair: low half is a small
// weight, exp<=~125; fp32: bits7..14 are mantissa bits, ~49% >= 130).
__global__ void k_detect(const unsigned* __restrict__ w, int* __restrict__ flag) {
  __shared__ int red[256];
  const int t = threadIdx.x;
  int c = 0;
  for (int i = t; i < 4096; i += 256) c += (((w[i] >> 7) & 0xFFu) >= 130u) ? 1 : 0;
  red[t] = c;
  __syncthreads();
  for (int s = 128; s > 0; s >>= 1) {
    if (t < s) red[t] += red[t + s];
    __syncthreads();
  }
  if (t == 0) flag[0] = (red[0] > 100) ? 1 : 0;  // 1 = fp32 inputs
}

// Fused small prep: bias convert (blocks 0..5), W transposes (6..773),
// X -> bf16 copy Xc (774.., 4 elems/thread).
__global__ void k_prep(const void* b1, const void* b2, const void* b3,
                       const void* W1, const void* W2, const void* W3,
                       const void* X, const int* __restrict__ flag,
                       float* __restrict__ bc, bf16* __restrict__ Wt,
                       bf16* __restrict__ xc) {
  __shared__ float tile[32][33];
  const int bid = blockIdx.x;
  const int t = threadIdx.x;
  const int f = flag[0];
  if (bid < 6) {
    const int j = bid * 256 + t;  // 0..1535
    const void* src = (j < 512) ? b1 : (j < 1024 ? b2 : b3);
    bc[j] = rdv(src, (size_t)(j & 511), f);
  } else if (bid < 774) {
    const int bid2 = bid - 6;
    const int z = bid2 >> 8, ti = bid2 & 255;
    const int f0 = (ti & 15) * 32, k0 = (ti >> 4) * 32;
    const int tx = t & 31, ty = t >> 5;
    const void* W = (z == 0) ? W1 : ((z == 1) ? W2 : W3);
    bf16* dst = Wt + (size_t)z * F_ * F_;
#pragma unroll
    for (int s = 0; s < 4; ++s)
      tile[ty + 8 * s][tx] = rdv(W, (size_t)(k0 + ty + 8 * s) * F_ + f0 + tx, f);
    __syncthreads();
#pragma unroll
    for (int s = 0; s < 4; ++s)
      dst[(size_t)(f0 + ty + 8 * s) * F_ + k0 + tx] = (bf16)tile[tx][ty + 8 * s];
  } else {
    const size_t i4 = ((size_t)(bid - 774) * 256 + t) * 4;
    if (f) {
      f32x4 v = *(const f32x4*)((const float*)X + i4);
      bf16 o[4] = {(bf16)v[0], (bf16)v[1], (bf16)v[2], (bf16)v[3]};
      *(ulong1*)&xc[i4] = *(ulong1*)o;  // 8B store
    } else {
      *(ulong1*)&xc[i4] = *(const ulong1*)((const bf16*)X + i4);  // bitcopy
    }
  }
}

// Fused transpose + column-sum partials:
//   adjT[b][i][j] = bf16(adj[b][j][i])
//   csp[j0/64][b][i] = sum_{j in [j0,j0+64)} adj[b][j][i]   (fp32, no atomics)
__global__ void k_tran(const void* adj, const int* __restrict__ flag,
                       bf16* __restrict__ adjT, float* __restrict__ csp) {
  __shared__ float tile[64][65];
  __shared__ float red[4][64];
  const int tx = threadIdx.x, ty = threadIdx.y;  // 16,16
  const int t = ty * 16 + tx;
  const int b = blockIdx.z, i0 = blockIdx.y * 64, j0 = blockIdx.x * 64;
  const size_t sb = (size_t)b * N_ * N_;
  if (flag[0]) {
    const float* src = (const float*)adj + sb;
#pragma unroll
    for (int s = 0; s < 4; ++s) {
      const int jj = ty + 16 * s;
      f32x4 v = *(const f32x4*)&src[(size_t)(j0 + jj) * N_ + i0 + 4 * tx];
#pragma unroll
      for (int u = 0; u < 4; ++u) tile[jj][4 * tx + u] = v[u];
    }
  } else {
    const bf16* src = (const bf16*)adj + sb;
#pragma unroll
    for (int s = 0; s < 4; ++s) {
      const int jj = ty + 16 * s;
      bf16x4 v = *(const bf16x4*)&src[(size_t)(j0 + jj) * N_ + i0 + 4 * tx];
#pragma unroll
      for (int u = 0; u < 4; ++u) tile[jj][4 * tx + u] = (float)v[u];
    }
  }
  __syncthreads();
  // column partial sums over this block's 64 rows (j), per column i
  {
    const int cc = t & 63, g = t >> 6;  // 64 cols x 4 row-groups
    float s = 0.f;
#pragma unroll
    for (int r = 0; r < 16; ++r) s += tile[g * 16 + r][cc];
    red[g][cc] = s;
  }
  // transposed write
  bf16* dst = adjT + sb;
#pragma unroll
  for (int s = 0; s < 4; ++s) {
    const int ii = ty + 16 * s;
    bf16x4 o;
#pragma unroll
    for (int u = 0; u < 4; ++u) o[u] = (bf16)tile[4 * tx + u][ii];
    *(bf16x4*)&dst[(size_t)(i0 + ii) * N_ + j0 + 4 * tx] = o;
  }
  __syncthreads();
  if (t < 64)
    csp[((size_t)(j0 >> 6) * B_ + b) * N_ + i0 + t] =
        red[0][t] + red[1][t] + red[2][t] + red[3][t];
}

// degree scale r = colsum^-1/2 (0 if <=0), colsum = sum of 16 csp slices
__device__ __forceinline__ float rscale(const float* __restrict__ csp, int b, int node) {
  float c = 0.f;
#pragma unroll
  for (int z = 0; z < 16; ++z) c += csp[((size_t)z * B_ + b) * N_ + node];
  return c > 0.f ? rsqrtf(c) : 0.f;
}

// C[M][Nc] = A[M][K] * Bt[Nc][K]^T, optional col scale (SCALEN: v*=r_n),
// row scale (SCALEM: v=r_m*v), bias, ReLU.
// 128x64 tile, BK=64, double-buffered LDS (48KB -> 3 blocks/CU), raw
// s_barrier pipeline w/ fine-grained vmcnt(6). Grid 1024 -> 12 waves/CU.
// 1-D grid, XCD swizzle: id%8 = XCD, 2 batches/XCD, 64 tiles/batch.
template <int BIAS, int RELU, int OUTDYN, int SCALEN, int SCALEM, int GX>
__global__ __launch_bounds__(256)
void k_gemm_bt(const bf16* __restrict__ A, const bf16* __restrict__ Bt,
               const float* __restrict__ bias, void* __restrict__ C,
               const int* __restrict__ flag, const float* __restrict__ csp,
               int Nc, int K, long sA, long sB, long sC) {
  __shared__ __align__(16) char smem[49664];  // 2x(As 16K + Bs 8K) + rsh 512B
  const int id = blockIdx.x;
  const int xcd = id & 7, p = id >> 3;        // p in 0..127
  const int bz = xcd * 2 + (p >> 6);
  const int tl = p & 63;
  const int bx = tl % GX, by = tl / GX;

  const int tid = threadIdx.x;
  const int wid = tid >> 6, lane = tid & 63;
  const int wm = wid >> 1, wn = wid & 1;
  const int quad = lane >> 4, l16 = lane & 15;
  const int rl = lane >> 3;               // 0..7 staging row within 8-row issue
  const int cg8 = ((lane & 7) ^ rl) * 8;  // swizzled global col offset (elems)
  const int h = l16 & 7;                  // fragment-read swizzle key

  const bf16* gA = A + (size_t)bz * sA + (size_t)by * 128 * K;
  const bf16* gB = Bt + (size_t)bz * sB + (size_t)bx * 64 * K;

  f32x4 acc[4][2];
#pragma unroll
  for (int i = 0; i < 4; ++i)
#pragma unroll
    for (int j = 0; j < 2; ++j) acc[i][j] = (f32x4){0.f, 0.f, 0.f, 0.f};

  auto stage = [&](int d, int k0) {
    bf16* As = (bf16*)(smem + d * 24576);
    bf16* Bs = (bf16*)(smem + d * 24576 + 16384);
#pragma unroll
    for (int i = 0; i < 4; ++i) {
      const int r0 = wid * 32 + i * 8;  // A rows: 4 waves x 32 = 128
      gld16(gA + (size_t)(r0 + rl) * K + k0 + cg8, &As[r0 * 64]);
    }
#pragma unroll
    for (int i = 0; i < 2; ++i) {
      const int r0 = wid * 16 + i * 8;  // B rows: 4 waves x 16 = 64
      gld16(gB + (size_t)(r0 + rl) * K + k0 + cg8, &Bs[r0 * 64]);
    }
  };

  stage(0, 0);
  for (int k0 = 0; k0 < K; k0 += 64) {
    const int cur = (k0 >> 6) & 1;
    if (k0 + 64 < K) {
      stage(1 - cur, k0 + 64);
      // wait only for tile-cur's 6 loads; prefetch (6 newest) stays in flight
      asm volatile("s_waitcnt vmcnt(6)\n\ts_barrier" ::: "memory");
    } else {
      asm volatile("s_waitcnt vmcnt(0)\n\ts_barrier" ::: "memory");
    }
    const bf16* As = (const bf16*)(smem + cur * 24576);
    const bf16* Bs = (const bf16*)(smem + cur * 24576 + 16384);
#pragma unroll
    for (int s = 0; s < 2; ++s) {
      bf16x8 af[4], bfv[2];
#pragma unroll
      for (int tm = 0; tm < 4; ++tm)
        af[tm] = *(const bf16x8*)&As[(wm * 64 + tm * 16 + l16) * 64 +
                                     (((quad + 4 * s) ^ h) * 8)];
#pragma unroll
      for (int tn = 0; tn < 2; ++tn)
        bfv[tn] = *(const bf16x8*)&Bs[(wn * 32 + tn * 16 + l16) * 64 +
                                      (((quad + 4 * s) ^ h) * 8)];
#pragma unroll
      for (int tm = 0; tm < 4; ++tm)
#pragma unroll
        for (int tn = 0; tn < 2; ++tn)
          acc[tm][tn] =
              __builtin_amdgcn_mfma_f32_16x16x32_bf16(af[tm], bfv[tn], acc[tm][tn], 0, 0, 0);
    }
    asm volatile("s_barrier" ::: "memory");  // WAR protect (exec barrier only)
  }

  // per-block scale table in LDS (K-loop LDS now free)
  float* rsh = (float*)(smem + 49152);
  if (SCALEM) {
    if (tid < 128) rsh[tid] = rscale(csp, bz, by * 128 + tid);
    __syncthreads();
  } else if (SCALEN) {
    if (tid < 64) rsh[tid] = rscale(csp, bz, bx * 64 + tid);
    __syncthreads();
  }

  // C/D layout: col = lane&15, row = quad*4 + reg  [m89/m91]
  const size_t cb = (size_t)bz * sC;
  const int mb_w = by * 128 + wm * 64;
  const int nb_w = bx * 64 + wn * 32;

  if (OUTDYN) {
    const int of32 = flag[0];
#pragma unroll
    for (int tn = 0; tn < 2; ++tn) {
      const int n = nb_w + tn * 16 + l16;
      float bv = BIAS ? bias[n] : 0.f;
      const float cscale = SCALEN ? rsh[wn * 32 + tn * 16 + l16] : 1.f;
#pragma unroll
      for (int tm = 0; tm < 4; ++tm) {
        const int m0 = mb_w + tm * 16 + quad * 4;
#pragma unroll
        for (int r = 0; r < 4; ++r) {
          float v = acc[tm][tn][r];
          if (SCALEM) v *= rsh[wm * 64 + tm * 16 + quad * 4 + r];
          if (SCALEN) v *= cscale;
          v += bv;
          if (RELU) v = v > 0.f ? v : 0.f;
          const size_t idx = cb + (size_t)(m0 + r) * Nc + n;
          if (of32) ((float*)C)[idx] = v;
          else      ((bf16*)C)[idx] = (bf16)v;
        }
      }
    }
  } else {
    // repack through per-wave LDS tile [64][40], then 16B coalesced stores
    bf16* W = (bf16*)smem + wid * (64 * 40);
#pragma unroll
    for (int tn = 0; tn < 2; ++tn) {
      const int n = nb_w + tn * 16 + l16;
      float bv = BIAS ? bias[n] : 0.f;
      const float cscale = SCALEN ? rsh[wn * 32 + tn * 16 + l16] : 1.f;
#pragma unroll
      for (int tm = 0; tm < 4; ++tm) {
#pragma unroll
        for (int r = 0; r < 4; ++r) {
          float v = acc[tm][tn][r];
          if (SCALEM) v *= rsh[wm * 64 + tm * 16 + quad * 4 + r];
          if (SCALEN) v *= cscale;
          v += bv;
          if (RELU) v = v > 0.f ? v : 0.f;
          W[(tm * 16 + quad * 4 + r) * 40 + tn * 16 + l16] = (bf16)v;
        }
      }
    }
    bf16* gC = (bf16*)C + cb;
#pragma unroll
    for (int i = 0; i < 4; ++i) {
      const int row = i * 16 + (lane >> 2);          // 16 rows per issue
      bf16x8 v = *(const bf16x8*)&W[row * 40 + (lane & 3) * 8];
      *(bf16x8*)&gC[(size_t)(mb_w + row) * Nc + nb_w + (lane & 3) * 8] = v;
    }
  }
}

extern "C" void kernel_launch(void* const* d_in, const int* in_sizes, int n_in,
                              void* d_out, int out_size, void* d_ws, size_t ws_size,
                              hipStream_t stream) {
  // ws: csp(1MB) | flag | bc | adjT(32MB) | Wt(1.5MB) | Zt(16MB)  ~50.5MB
  char* ws = (char*)d_ws;
  float* csp  = (float*)ws;                         // 1 MB [16][B][N]
  int*  flag  = (int*)(ws + 1048576);
  float* bc   = (float*)(ws + 1048832);             // 6 KB [3][512]
  bf16* adjT  = (bf16*)(ws + 1056768);              // 32 MB [B][N][N]
  bf16* Wt    = (bf16*)(ws + 1056768 + 33554432);   // 1.5 MB [3][F][F]
  bf16* Zt    = (bf16*)(ws + 1056768 + 33554432 + 3 * F_ * F_ * 2);  // 16 MB
  bf16* Xc = (bf16*)d_out;  // d_out doubles as bf16 activation scratch

  const long sW = 0;
  const long sX = (long)N_ * F_;
  const long sZ = (long)F_ * N_;
  const long sAn = (long)N_ * N_;

  k_detect<<<1, 256, 0, stream>>>((const unsigned*)d_in[2], flag);
  k_prep<<<774 + (B_ * N_ * F_) / 1024, 256, 0, stream>>>(
      d_in[3], d_in[5], d_in[7], d_in[2], d_in[4], d_in[6], d_in[0], flag, bc, Wt, Xc);
  k_tran<<<dim3(N_ / 64, N_ / 64, B_), dim3(16, 16), 0, stream>>>(d_in[1], flag, adjT, csp);

  // GEMM1: Zt = Wt_z @ Xc^T, cols scaled by r_j   (M=F=512, Nc=N, K=F, GX=16)
  // GEMM2: X' = r_i * (adjT @ Zt^T) + b, ReLU     (M=N=1024, Nc=F, K=N, GX=8)
  // layer 1
  k_gemm_bt<0, 0, 0, 1, 0, 16><<<1024, 256, 0, stream>>>(Wt,               Xc, nullptr,   Zt, flag, csp, N_, F_, sW, sX, sZ);
  k_gemm_bt<1, 1, 0, 0, 1, 8><<<1024, 256, 0, stream>>>(adjT,              Zt, bc,        Xc, flag, csp, F_, N_, sAn, sZ, sX);
  // layer 2
  k_gemm_bt<0, 0, 0, 1, 0, 16><<<1024, 256, 0, stream>>>(Wt + F_ * F_,     Xc, nullptr,   Zt, flag, csp, N_, F_, sW, sX, sZ);
  k_gemm_bt<1, 1, 0, 0, 1, 8><<<1024, 256, 0, stream>>>(adjT,              Zt, bc + 512,  Xc, flag, csp, F_, N_, sAn, sZ, sX);
  // layer 3
  k_gemm_bt<0, 0, 0, 1, 0, 16><<<1024, 256, 0, stream>>>(Wt + 2 * F_ * F_, Xc, nullptr,   Zt, flag, csp, N_, F_, sW, sX, sZ);
  k_gemm_bt<1, 0, 1, 0, 1, 8><<<1024, 256, 0, stream>>>(adjT,              Zt, bc + 1024, d_out, flag, csp, F_, N_, sAn, sZ, sX);
}